// Round 9
// baseline (609.901 us; speedup 1.0000x reference)
//
#include <hip/hip_runtime.h>

// DownSample — bf16 MFMA implicit-GEMM, gather form, zero-row trick.
// v9r: identical to v9 (round-8 bench died in the container broker before
//     running — no kernel evidence). v8 (591 µs; conv2_k=186) + km staged
//     into LDS one tap ahead via global_load_lds (4B/lane, per-lane clamped
//     source address, wave-uniform LDS dest), read back with a ~120cy
//     conflict-free ds_read instead of a ~900cy streamed global load.
//     Removes the km half of the measured ~2040 cyc/tap critical chain
//     (barrier->km->gather->MFMA) with ZERO register carrying (v2/v6's
//     failure mode) and zero extra sync (the existing per-tap barrier
//     already covers the stage). Everything else byte-identical to v8.
//
// Dense over all taps (27 conv / 8 pool); invalid neighbors index an appended
// all-zero row -> branch-free MFMA. fp32 accumulate, bn+relu fused in epilogue.
// Verified fragment mappings (gfx950 16x16x32 bf16):
//   A[m=lane&15][k=(lane>>4)*8+j]   B[k=(lane>>4)*8+j][n=lane&15]
//   C/D: n=lane&15, m=(lane>>4)*4+reg

#define NV 400000
#define ND 100000

typedef __attribute__((ext_vector_type(8))) short  bf16x8;
typedef __attribute__((ext_vector_type(4))) float  f32x4;

__device__ __forceinline__ unsigned short f2b(float f) {
    unsigned int u = __builtin_bit_cast(unsigned int, f);
    u += 0x7fffu + ((u >> 16) & 1u);          // round-to-nearest-even
    return (unsigned short)(u >> 16);
}

// ---- prep: fp32 -> bf16 bits, 4 at a time ---------------------------------
__global__ __launch_bounds__(256) void cvt_bf16_k(
    const float* __restrict__ in, unsigned short* __restrict__ out, int n)
{
    int t = (blockIdx.x * 256 + threadIdx.x) * 4;
    if (t >= n) return;
    float4 f = *(const float4*)(in + t);
    ushort4 u;
    u.x = f2b(f.x); u.y = f2b(f.y); u.z = f2b(f.z); u.w = f2b(f.w);
    *(ushort4*)(out + t) = u;
}

// ---- prep: pack W[nk][ci][64] fp32 into per-lane B fragments --------------
// layout: frag index ((k*steps + s)*4 + nt)*64 + lane, 8 bf16 each
__global__ __launch_bounds__(256) void pack_w_k(
    const float* __restrict__ W, unsigned short* __restrict__ out, int nk, int ci)
{
    int t = blockIdx.x * 256 + threadIdx.x;
    int steps = ci >> 5;
    if (t >= nk * steps * 4 * 64) return;
    int lane = t & 63;
    int nt   = (t >> 6) & 3;
    int rest = t >> 8;
    int s    = rest % steps;
    int k    = rest / steps;
    int col = lane & 15, quad = lane >> 4;
    int co = nt * 16 + col;
    unsigned short v[8];
#pragma unroll
    for (int j = 0; j < 8; ++j) {
        int cidx = s * 32 + quad * 8 + j;
        v[j] = f2b(W[((size_t)k * ci + cidx) * 64 + co]);
    }
    bf16x8 frag;
#pragma unroll
    for (int j = 0; j < 8; ++j) frag[j] = (short)v[j];
    *(bf16x8*)(out + (size_t)t * 8) = frag;
}

// ---- prep: invert kp maps -> ck[kk][parent] = child row (or NV sentinel) --
// transposed layout so the pool's j-loads are coalesced like the conv's
__global__ __launch_bounds__(256) void ck_init_k(int* __restrict__ ck)
{
    int t = blockIdx.x * 256 + threadIdx.x;
    if (t < ND * 8) ck[t] = NV;
}
__global__ __launch_bounds__(256) void ck_scatter_k(
    const int* __restrict__ kp_in, const int* __restrict__ kp_out,
    int* __restrict__ ck)
{
    int t = blockIdx.x * 256 + threadIdx.x;
    if (t >= 8 * NV) return;
    int j = kp_in[t];
    if (j == NV) return;
    int k = t / NV;
    ck[(size_t)k * ND + kp_out[t]] = j;
}

// ---- unified gather-GEMM body: wave computes 64 rows x 64 channels --------
// MODE: 0 = f32 out, 1 = bf16 out, 2 = both (outf + outb)
template <int CI, int NK, int MODE, int NR>
__device__ __forceinline__ void conv_body(
    const unsigned short* __restrict__ xin,   // [(NV+1)][CI] bf16, row NV = 0
    const unsigned short* __restrict__ Wp,    // packed frags
    const int* __restrict__ km,               // [NK][NR], sentinel NV
    const float* __restrict__ bns, const float* __restrict__ bnb,
    float* __restrict__ outf, unsigned short* __restrict__ outb)
{
    constexpr int STEPS = CI / 32;
    constexpr int FR = STEPS * 4;             // B fragments per tap
    __shared__ unsigned short bsh[2 * FR * 512];   // dbuf x FR frags x 64 lanes x 8
    __shared__ int jsh[2][256];               // dbuf x block's km slice

    const int lane = threadIdx.x & 63;
    const int wave = threadIdx.x >> 6;
    const int col = lane & 15, quad = lane >> 4;

    // bijective XCD-chunked swizzle (m204): works for any gridDim
    const int nwg = gridDim.x;
    const int q = nwg >> 3, r = nwg & 7;
    const int xcd = blockIdx.x & 7, bodd = blockIdx.x >> 3;
    const int bid = (xcd < r ? xcd * (q + 1) : r * (q + 1) + (xcd - r) * q) + bodd;

    const int wbase = (bid * 4 + wave) * 64;

    // per-lane clamped source row for km staging (edge blocks read NR-1,
    // matching the old rowm clamp semantics exactly)
    const int srow = (wbase + lane < NR) ? wbase + lane : NR - 1;

    f32x4 acc[4][4];
#pragma unroll
    for (int mt = 0; mt < 4; ++mt)
#pragma unroll
        for (int nt = 0; nt < 4; ++nt) acc[mt][nt] = (f32x4)0.f;

    // stage tap k's B tile + km slice into LDS buffer b.
    // B: waves split the frags, dest = wave-uniform base + lane*16B.
    // km: each wave stages its own 64 rows, dest = wave-uniform + lane*4B;
    //     the global SOURCE address is per-lane (clamped) — legal per m173.
    auto stage = [&](int k, int b) {
#pragma unroll
        for (int f = wave; f < FR; f += 4) {
            const unsigned short* src = Wp + ((size_t)(k * FR + f) * 64 + lane) * 8;
            __builtin_amdgcn_global_load_lds(
                (const __attribute__((address_space(1))) void*)src,
                (__attribute__((address_space(3))) void*)&bsh[b * (FR * 512) + f * 512],
                16, 0, 0);
        }
        const int* psrc = km + (size_t)k * NR + srow;
        __builtin_amdgcn_global_load_lds(
            (const __attribute__((address_space(1))) void*)psrc,
            (__attribute__((address_space(3))) void*)&jsh[b][wave * 64],
            4, 0, 0);
    };

    stage(0, 0);
    int buf = 0;

    for (int k = 0; k < NK; ++k) {
        __syncthreads();                       // stage(k) complete (vmcnt drained)
        if (k + 1 < NK) stage(k + 1, buf ^ 1);

        // j from LDS (~120cy, conflict-free) instead of streamed global (~900cy)
        int j[4];
#pragma unroll
        for (int mt = 0; mt < 4; ++mt)
            j[mt] = jsh[buf][wave * 64 + mt * 16 + col];

#pragma unroll
        for (int s = 0; s < STEPS; ++s) {
            bf16x8 a[4];
#pragma unroll
            for (int mt = 0; mt < 4; ++mt)
                a[mt] = *(const bf16x8*)(xin + (size_t)j[mt] * CI + s * 32 + quad * 8);
#pragma unroll
            for (int nt = 0; nt < 4; ++nt) {
                bf16x8 b = *(const bf16x8*)&bsh[buf * (FR * 512) + (s * 4 + nt) * 512 + lane * 8];
#pragma unroll
                for (int mt = 0; mt < 4; ++mt)
                    acc[mt][nt] = __builtin_amdgcn_mfma_f32_16x16x32_bf16(
                        a[mt], b, acc[mt][nt], 0, 0, 0);
            }
        }
        buf ^= 1;
    }

    // ---- epilogue: bn + relu, store ----
#pragma unroll
    for (int nt = 0; nt < 4; ++nt) {
        const int n = nt * 16 + col;
        const float sc = bns[n], bi = bnb[n];
#pragma unroll
        for (int mt = 0; mt < 4; ++mt)
#pragma unroll
            for (int rr = 0; rr < 4; ++rr) {
                int row = wbase + mt * 16 + quad * 4 + rr;
                if (row < NR) {
                    float v = fmaxf(fmaf(acc[mt][nt][rr], sc, bi), 0.f);
                    if constexpr (MODE == 0) {
                        outf[(size_t)row * 64 + n] = v;
                    } else if constexpr (MODE == 1) {
                        outb[(size_t)row * 64 + n] = f2b(v);
                    } else {
                        outf[(size_t)row * 64 + n] = v;
                        outb[(size_t)row * 64 + n] = f2b(v);
                    }
                }
            }
    }
}

// ---- distinctly-named stage kernels (for per-stage rocprof attribution) ---
__global__ __launch_bounds__(256) void conv1_k(
    const unsigned short* __restrict__ xin, const unsigned short* __restrict__ Wp,
    const int* __restrict__ km, const float* __restrict__ bns,
    const float* __restrict__ bnb, unsigned short* __restrict__ outb)
{
    conv_body<32, 27, 1, NV>(xin, Wp, km, bns, bnb, nullptr, outb);
}
__global__ __launch_bounds__(256) void conv2_k(
    const unsigned short* __restrict__ xin, const unsigned short* __restrict__ Wp,
    const int* __restrict__ km, const float* __restrict__ bns,
    const float* __restrict__ bnb, float* __restrict__ outf,
    unsigned short* __restrict__ outb)
{
    conv_body<64, 27, 2, NV>(xin, Wp, km, bns, bnb, outf, outb);
}
__global__ __launch_bounds__(256) void pool_k(
    const unsigned short* __restrict__ xin, const unsigned short* __restrict__ Wp,
    const int* __restrict__ ck, const float* __restrict__ bns,
    const float* __restrict__ bnb, float* __restrict__ outf)
{
    conv_body<64, 8, 0, ND>(xin, Wp, ck, bns, bnb, outf, nullptr);
}

extern "C" void kernel_launch(void* const* d_in, const int* in_sizes, int n_in,
                              void* d_out, int out_size, void* d_ws, size_t ws_size,
                              hipStream_t stream)
{
    const float* x    = (const float*)d_in[0];
    const float* W1   = (const float*)d_in[1];
    const float* bn1s = (const float*)d_in[2];
    const float* bn1b = (const float*)d_in[3];
    const float* W2   = (const float*)d_in[4];
    const float* bn2s = (const float*)d_in[5];
    const float* bn2b = (const float*)d_in[6];
    const float* Wp   = (const float*)d_in[7];
    const float* bnps = (const float*)d_in[8];
    const float* bnpb = (const float*)d_in[9];
    const int* km_in  = (const int*)d_in[10];
    const int* kp_in  = (const int*)d_in[12];
    const int* kp_out = (const int*)d_in[13];

    float* down = (float*)d_out;                     // [NV,64] output 0
    float* pout = (float*)d_out + (size_t)NV * 64;   // [ND,64] output 1

    char* ws = (char*)d_ws;
    unsigned short* x_bf  = (unsigned short*)ws;  ws += (size_t)(NV + 1) * 32 * 2; // 25.6MB
    unsigned short* h_bf  = (unsigned short*)ws;  ws += (size_t)(NV + 1) * 64 * 2; // 51.2MB
    unsigned short* d_bf  = (unsigned short*)ws;  ws += (size_t)(NV + 1) * 64 * 2; // 51.2MB
    int*            ck    = (int*)ws;             ws += (size_t)8 * ND * 4;        // 3.2MB
    unsigned short* W1p   = (unsigned short*)ws;  ws += (size_t)27 * 32 * 64 * 2;
    unsigned short* W2p   = (unsigned short*)ws;  ws += (size_t)27 * 64 * 64 * 2;
    unsigned short* Wpp   = (unsigned short*)ws;

    // zero rows (re-poisoned to 0xAA before every timed call)
    hipMemsetAsync(x_bf + (size_t)NV * 32, 0, 32 * 2, stream);
    hipMemsetAsync(h_bf + (size_t)NV * 64, 0, 64 * 2, stream);
    hipMemsetAsync(d_bf + (size_t)NV * 64, 0, 64 * 2, stream);

    cvt_bf16_k<<<(NV * 32 / 4 + 255) / 256, 256, 0, stream>>>(x, x_bf, NV * 32);
    pack_w_k<<<(27 * 1 * 4 * 64 + 255) / 256, 256, 0, stream>>>(W1, W1p, 27, 32);
    pack_w_k<<<(27 * 2 * 4 * 64 + 255) / 256, 256, 0, stream>>>(W2, W2p, 27, 64);
    pack_w_k<<<(8  * 2 * 4 * 64 + 255) / 256, 256, 0, stream>>>(Wp, Wpp, 8, 64);
    ck_init_k<<<(ND * 8 + 255) / 256, 256, 0, stream>>>(ck);
    ck_scatter_k<<<(8 * NV + 255) / 256, 256, 0, stream>>>(kp_in, kp_out, ck);

    const int cgrid = (NV + 255) / 256;
    conv1_k<<<cgrid, 256, 0, stream>>>(x_bf, W1p, km_in, bn1s, bn1b, h_bf);
    conv2_k<<<cgrid, 256, 0, stream>>>(h_bf, W2p, km_in, bn2s, bn2b, down, d_bf);
    pool_k<<<(ND + 255) / 256, 256, 0, stream>>>(d_bf, Wpp, ck, bnps, bnpb, pout);
}

// Round 10
// 589.660 us; speedup vs baseline: 1.0343x; 1.0343x over previous
//
#include <hip/hip_runtime.h>

// DownSample — bf16 MFMA implicit-GEMM, gather form, zero-row trick.
// v10: software-pipelined gathers, barrier-enforced. v9 measured the chain as
//     gather-dominated (~65% stall cycles; km-stage gave only -5%). Now km is
//     staged TWO taps ahead, so j(k+1) is readable at the START of iter k and
//     the a(k+1) gathers issue into an alternate register set BEFORE tap k's
//     MFMA — a full iteration + barrier of flight time. The per-tap barrier
//     both drains and ENFORCES the pipeline (compiler cannot sink loads
//     across __syncthreads — the guarantee v2/v6's register carrying lacked).
//     Manual unroll-by-2 with named aP/aQ buffers: no rotate-copies, all
//     static indexing. B staging cadence unchanged from v9.
//     + pack_w launches fused 3->1 (launch-gap harvest, attribution separate).
//
// Dense over all taps (27 conv / 8 pool); invalid neighbors index an appended
// all-zero row -> branch-free MFMA. fp32 accumulate, bn+relu fused in epilogue.
// Verified fragment mappings (gfx950 16x16x32 bf16):
//   A[m=lane&15][k=(lane>>4)*8+j]   B[k=(lane>>4)*8+j][n=lane&15]
//   C/D: n=lane&15, m=(lane>>4)*4+reg

#define NV 400000
#define ND 100000

typedef __attribute__((ext_vector_type(8))) short  bf16x8;
typedef __attribute__((ext_vector_type(4))) float  f32x4;

__device__ __forceinline__ unsigned short f2b(float f) {
    unsigned int u = __builtin_bit_cast(unsigned int, f);
    u += 0x7fffu + ((u >> 16) & 1u);          // round-to-nearest-even
    return (unsigned short)(u >> 16);
}

// ---- prep: fp32 -> bf16 bits, 4 at a time ---------------------------------
__global__ __launch_bounds__(256) void cvt_bf16_k(
    const float* __restrict__ in, unsigned short* __restrict__ out, int n)
{
    int t = (blockIdx.x * 256 + threadIdx.x) * 4;
    if (t >= n) return;
    float4 f = *(const float4*)(in + t);
    ushort4 u;
    u.x = f2b(f.x); u.y = f2b(f.y); u.z = f2b(f.z); u.w = f2b(f.w);
    *(ushort4*)(out + t) = u;
}

// ---- prep: pack W[nk][ci][64] fp32 into per-lane B fragments --------------
// layout: frag index ((k*steps + s)*4 + nt)*64 + lane, 8 bf16 each
__device__ __forceinline__ void pack_one(
    const float* __restrict__ W, unsigned short* __restrict__ out,
    int ci, int t)
{
    int steps = ci >> 5;
    int lane = t & 63;
    int nt   = (t >> 6) & 3;
    int rest = t >> 8;
    int s    = rest % steps;
    int k    = rest / steps;
    int col = lane & 15, quad = lane >> 4;
    int co = nt * 16 + col;
    bf16x8 frag;
#pragma unroll
    for (int j = 0; j < 8; ++j) {
        int cidx = s * 32 + quad * 8 + j;
        frag[j] = (short)f2b(W[((size_t)k * ci + cidx) * 64 + co]);
    }
    *(bf16x8*)(out + (size_t)t * 8) = frag;
}
__global__ __launch_bounds__(256) void pack_all_k(
    const float* __restrict__ W1, unsigned short* __restrict__ W1p,
    const float* __restrict__ W2, unsigned short* __restrict__ W2p,
    const float* __restrict__ Wp, unsigned short* __restrict__ Wpp)
{
    int t = blockIdx.x * 256 + threadIdx.x;
    constexpr int N1 = 27 * 1 * 4 * 64;      // 6912
    constexpr int N2 = 27 * 2 * 4 * 64;      // 13824
    constexpr int N3 = 8  * 2 * 4 * 64;      // 4096
    if (t < N1)                 pack_one(W1, W1p, 32, t);
    else if (t < N1 + N2)       pack_one(W2, W2p, 64, t - N1);
    else if (t < N1 + N2 + N3)  pack_one(Wp, Wpp, 64, t - N1 - N2);
}

// ---- prep: invert kp maps -> ck[kk][parent] = child row (or NV sentinel) --
// transposed layout so the pool's j-loads are coalesced like the conv's
__global__ __launch_bounds__(256) void ck_init_k(int* __restrict__ ck)
{
    int t = blockIdx.x * 256 + threadIdx.x;
    if (t < ND * 8) ck[t] = NV;
}
__global__ __launch_bounds__(256) void ck_scatter_k(
    const int* __restrict__ kp_in, const int* __restrict__ kp_out,
    int* __restrict__ ck)
{
    int t = blockIdx.x * 256 + threadIdx.x;
    if (t >= 8 * NV) return;
    int j = kp_in[t];
    if (j == NV) return;
    int k = t / NV;
    ck[(size_t)k * ND + kp_out[t]] = j;
}

// ---- unified gather-GEMM body: wave computes 64 rows x 64 channels --------
// MODE: 0 = f32 out, 1 = bf16 out, 2 = both (outf + outb)
template <int CI, int NK, int MODE, int NR>
__device__ __forceinline__ void conv_body(
    const unsigned short* __restrict__ xin,   // [(NV+1)][CI] bf16, row NV = 0
    const unsigned short* __restrict__ Wp,    // packed frags
    const int* __restrict__ km,               // [NK][NR], sentinel NV
    const float* __restrict__ bns, const float* __restrict__ bnb,
    float* __restrict__ outf, unsigned short* __restrict__ outb)
{
    constexpr int STEPS = CI / 32;
    constexpr int FR = STEPS * 4;             // B fragments per tap
    __shared__ unsigned short bsh[2 * FR * 512];   // dbuf x FR frags x 64 lanes x 8
    __shared__ int jsh[2][256];               // dbuf x block's km slice

    const int lane = threadIdx.x & 63;
    const int wave = threadIdx.x >> 6;
    const int col = lane & 15, quad = lane >> 4;

    // bijective XCD-chunked swizzle (m204): works for any gridDim
    const int nwg = gridDim.x;
    const int q = nwg >> 3, r = nwg & 7;
    const int xcd = blockIdx.x & 7, bodd = blockIdx.x >> 3;
    const int bid = (xcd < r ? xcd * (q + 1) : r * (q + 1) + (xcd - r) * q) + bodd;

    const int wbase = (bid * 4 + wave) * 64;

    // per-lane clamped source row for km staging (edge blocks read NR-1,
    // matching the old rowm clamp semantics exactly)
    const int srow = (wbase + lane < NR) ? wbase + lane : NR - 1;

    f32x4 acc[4][4];
#pragma unroll
    for (int mt = 0; mt < 4; ++mt)
#pragma unroll
        for (int nt = 0; nt < 4; ++nt) acc[mt][nt] = (f32x4)0.f;

    // B tile of tap k -> LDS buf b (waves split frags; dest wave-uniform+lane*16)
    auto stage_b = [&](int k, int b) {
#pragma unroll
        for (int f = wave; f < FR; f += 4) {
            const unsigned short* src = Wp + ((size_t)(k * FR + f) * 64 + lane) * 8;
            __builtin_amdgcn_global_load_lds(
                (const __attribute__((address_space(1))) void*)src,
                (__attribute__((address_space(3))) void*)&bsh[b * (FR * 512) + f * 512],
                16, 0, 0);
        }
    };
    // km slice of tap k -> jsh[k&1] (per-lane clamped SOURCE, uniform dest)
    auto stage_km = [&](int k) {
        const int* psrc = km + (size_t)k * NR + srow;
        __builtin_amdgcn_global_load_lds(
            (const __attribute__((address_space(1))) void*)psrc,
            (__attribute__((address_space(3))) void*)&jsh[k & 1][wave * 64],
            4, 0, 0);
    };

    // ---- prologue: B(0), km(0), km(1) staged; a(0) gathered ----
    stage_b(0, 0);
    stage_km(0);
    stage_km(1);
    __syncthreads();

    bf16x8 aP[STEPS][4], aQ[STEPS][4];
    {
        int j0[4];
#pragma unroll
        for (int mt = 0; mt < 4; ++mt)
            j0[mt] = jsh[0][wave * 64 + mt * 16 + col];
#pragma unroll
        for (int s = 0; s < STEPS; ++s)
#pragma unroll
            for (int mt = 0; mt < 4; ++mt)
                aP[s][mt] = *(const bf16x8*)(
                    xin + (size_t)j0[mt] * CI + s * 32 + quad * 8);
    }

    // ---- steady state: issue a(k+1)/B(k+1)/km(k+2), MFMA(k), barrier ----
    auto body = [&](int k, bf16x8 (&aIn)[STEPS][4], bf16x8 (&aOut)[STEPS][4]) {
        if (k + 1 < NK) {
            int jn[4];
#pragma unroll
            for (int mt = 0; mt < 4; ++mt)
                jn[mt] = jsh[(k + 1) & 1][wave * 64 + mt * 16 + col];
#pragma unroll
            for (int s = 0; s < STEPS; ++s)
#pragma unroll
                for (int mt = 0; mt < 4; ++mt)
                    aOut[s][mt] = *(const bf16x8*)(
                        xin + (size_t)jn[mt] * CI + s * 32 + quad * 8);
            stage_b(k + 1, (k + 1) & 1);
            if (k + 2 < NK) stage_km(k + 2);
        }
#pragma unroll
        for (int s = 0; s < STEPS; ++s)
#pragma unroll
            for (int nt = 0; nt < 4; ++nt) {
                bf16x8 b = *(const bf16x8*)&bsh[(k & 1) * (FR * 512)
                                                + (s * 4 + nt) * 512 + lane * 8];
#pragma unroll
                for (int mt = 0; mt < 4; ++mt)
                    acc[mt][nt] = __builtin_amdgcn_mfma_f32_16x16x32_bf16(
                        aIn[s][mt], b, acc[mt][nt], 0, 0, 0);
            }
        __syncthreads();   // drains a(k+1), B(k+1), km(k+2); guards LDS reuse
    };

    for (int kk = 0; kk < NK / 2; ++kk) {
        body(2 * kk,     aP, aQ);
        body(2 * kk + 1, aQ, aP);
    }
    if constexpr (NK & 1) body(NK - 1, aP, aQ);

    // ---- epilogue: bn + relu, store ----
#pragma unroll
    for (int nt = 0; nt < 4; ++nt) {
        const int n = nt * 16 + col;
        const float sc = bns[n], bi = bnb[n];
#pragma unroll
        for (int mt = 0; mt < 4; ++mt)
#pragma unroll
            for (int rr = 0; rr < 4; ++rr) {
                int row = wbase + mt * 16 + quad * 4 + rr;
                if (row < NR) {
                    float v = fmaxf(fmaf(acc[mt][nt][rr], sc, bi), 0.f);
                    if constexpr (MODE == 0) {
                        outf[(size_t)row * 64 + n] = v;
                    } else if constexpr (MODE == 1) {
                        outb[(size_t)row * 64 + n] = f2b(v);
                    } else {
                        outf[(size_t)row * 64 + n] = v;
                        outb[(size_t)row * 64 + n] = f2b(v);
                    }
                }
            }
    }
}

// ---- distinctly-named stage kernels (for per-stage rocprof attribution) ---
__global__ __launch_bounds__(256, 2) void conv1_k(
    const unsigned short* __restrict__ xin, const unsigned short* __restrict__ Wp,
    const int* __restrict__ km, const float* __restrict__ bns,
    const float* __restrict__ bnb, unsigned short* __restrict__ outb)
{
    conv_body<32, 27, 1, NV>(xin, Wp, km, bns, bnb, nullptr, outb);
}
__global__ __launch_bounds__(256, 2) void conv2_k(
    const unsigned short* __restrict__ xin, const unsigned short* __restrict__ Wp,
    const int* __restrict__ km, const float* __restrict__ bns,
    const float* __restrict__ bnb, float* __restrict__ outf,
    unsigned short* __restrict__ outb)
{
    conv_body<64, 27, 2, NV>(xin, Wp, km, bns, bnb, outf, outb);
}
__global__ __launch_bounds__(256, 2) void pool_k(
    const unsigned short* __restrict__ xin, const unsigned short* __restrict__ Wp,
    const int* __restrict__ ck, const float* __restrict__ bns,
    const float* __restrict__ bnb, float* __restrict__ outf)
{
    conv_body<64, 8, 0, ND>(xin, Wp, ck, bns, bnb, outf, nullptr);
}

extern "C" void kernel_launch(void* const* d_in, const int* in_sizes, int n_in,
                              void* d_out, int out_size, void* d_ws, size_t ws_size,
                              hipStream_t stream)
{
    const float* x    = (const float*)d_in[0];
    const float* W1   = (const float*)d_in[1];
    const float* bn1s = (const float*)d_in[2];
    const float* bn1b = (const float*)d_in[3];
    const float* W2   = (const float*)d_in[4];
    const float* bn2s = (const float*)d_in[5];
    const float* bn2b = (const float*)d_in[6];
    const float* Wp   = (const float*)d_in[7];
    const float* bnps = (const float*)d_in[8];
    const float* bnpb = (const float*)d_in[9];
    const int* km_in  = (const int*)d_in[10];
    const int* kp_in  = (const int*)d_in[12];
    const int* kp_out = (const int*)d_in[13];

    float* down = (float*)d_out;                     // [NV,64] output 0
    float* pout = (float*)d_out + (size_t)NV * 64;   // [ND,64] output 1

    char* ws = (char*)d_ws;
    unsigned short* x_bf  = (unsigned short*)ws;  ws += (size_t)(NV + 1) * 32 * 2; // 25.6MB
    unsigned short* h_bf  = (unsigned short*)ws;  ws += (size_t)(NV + 1) * 64 * 2; // 51.2MB
    unsigned short* d_bf  = (unsigned short*)ws;  ws += (size_t)(NV + 1) * 64 * 2; // 51.2MB
    int*            ck    = (int*)ws;             ws += (size_t)8 * ND * 4;        // 3.2MB
    unsigned short* W1p   = (unsigned short*)ws;  ws += (size_t)27 * 32 * 64 * 2;
    unsigned short* W2p   = (unsigned short*)ws;  ws += (size_t)27 * 64 * 64 * 2;
    unsigned short* Wpp   = (unsigned short*)ws;

    // zero rows (re-poisoned to 0xAA before every timed call)
    hipMemsetAsync(x_bf + (size_t)NV * 32, 0, 32 * 2, stream);
    hipMemsetAsync(h_bf + (size_t)NV * 64, 0, 64 * 2, stream);
    hipMemsetAsync(d_bf + (size_t)NV * 64, 0, 64 * 2, stream);

    cvt_bf16_k<<<(NV * 32 / 4 + 255) / 256, 256, 0, stream>>>(x, x_bf, NV * 32);
    pack_all_k<<<(27 * 4 * 64 * 3 + 8 * 2 * 4 * 64 + 255) / 256, 256, 0, stream>>>(
        W1, W1p, W2, W2p, Wp, Wpp);
    ck_init_k<<<(ND * 8 + 255) / 256, 256, 0, stream>>>(ck);
    ck_scatter_k<<<(8 * NV + 255) / 256, 256, 0, stream>>>(kp_in, kp_out, ck);

    const int cgrid = (NV + 255) / 256;
    conv1_k<<<cgrid, 256, 0, stream>>>(x_bf, W1p, km_in, bn1s, bn1b, h_bf);
    conv2_k<<<cgrid, 256, 0, stream>>>(h_bf, W2p, km_in, bn2s, bn2b, down, d_bf);
    pool_k<<<(ND + 255) / 256, 256, 0, stream>>>(d_bf, Wpp, ck, bnps, bnpb, pout);
}